// Round 1
// baseline (645.252 us; speedup 1.0000x reference)
//
#include <hip/hip_runtime.h>

typedef unsigned short u16;
typedef unsigned int   u32;
typedef short bf16x8 __attribute__((ext_vector_type(8)));
typedef float f32x4  __attribute__((ext_vector_type(4)));

__device__ __forceinline__ u16 f2bf(float f) {
  union { float f; u32 u; } v; v.f = f;
  u32 u = v.u;
  u += 0x7fffu + ((u >> 16) & 1u);   // RNE
  return (u16)(u >> 16);
}

// ---------------------------------------------------------------------------
// Prep: transposed / zero-padded weight layouts.
//   W1aT[160][768]  f32   (aW1^T)         W2aT[160][152] f32 (aW2^T)
//   mW1T/WaT/WbT[160][2304] f32           mW2T[160][152] f32
//   WcT[160][2304]  bf16  (pW1 rows 4608..)  W2pT[160][160] bf16 (pW2^T)
// ---------------------------------------------------------------------------
__global__ __launch_bounds__(256) void k_prep(
    const float* __restrict__ aW1, const float* __restrict__ aW2,
    const float* __restrict__ mW1, const float* __restrict__ mW2,
    const float* __restrict__ pW1, const float* __restrict__ pW2,
    float* __restrict__ W1aT, float* __restrict__ W2aT,
    float* __restrict__ mW1T, float* __restrict__ WaT,
    float* __restrict__ WbT,  float* __restrict__ mW2T,
    u16* __restrict__ WcT,    u16* __restrict__ W2pT) {
  const int stride = gridDim.x * blockDim.x;
  const int t0 = blockIdx.x * blockDim.x + threadIdx.x;
  for (int t = t0; t < 160*768; t += stride) {
    int h = t / 768, e = t % 768;
    W1aT[t] = (h < 150) ? aW1[e*150 + h] : 0.f;
  }
  for (int t = t0; t < 160*152; t += stride) {
    int h = t / 152, k = t % 152;
    W2aT[t] = (h < 150 && k < 150) ? aW2[k*150 + h] : 0.f;
    mW2T[t] = (h < 150 && k < 150) ? mW2[k*150 + h] : 0.f;
  }
  for (int t = t0; t < 160*2304; t += stride) {
    int h = t / 2304, e = t % 2304;
    bool val = (h < 150);
    mW1T[t] = val ? mW1[e*150 + h] : 0.f;
    WaT[t]  = val ? pW1[e*150 + h] : 0.f;
    WbT[t]  = val ? pW1[(2304 + e)*150 + h] : 0.f;
    WcT[t]  = val ? f2bf(pW1[(4608 + e)*150 + h]) : (u16)0;
  }
  for (int t = t0; t < 160*160; t += stride) {
    int h2 = t / 160, h1 = t % 160;
    W2pT[t] = (h2 < 150 && h1 < 150) ? f2bf(pW2[h1*150 + h2]) : (u16)0;
  }
}

// ---------------------------------------------------------------------------
// Attention MLP: attn[t] = mlp(e[t]). 8 tokens per block, 256 blocks. fp32.
// ---------------------------------------------------------------------------
__global__ __launch_bounds__(256) void k_attn(
    const float* __restrict__ e, const float* __restrict__ W1T,
    const float* __restrict__ b1, const float* __restrict__ W2T,
    const float* __restrict__ b2, const float* __restrict__ w3,
    const float* __restrict__ b3, float* __restrict__ attn) {
  __shared__ float xs[8][768];
  __shared__ float h1s[8][152];
  __shared__ float h2s[8][152];
  const int tid = threadIdx.x;
  const int t0 = blockIdx.x * 8;
  {
    const float4* src = (const float4*)(e + (size_t)t0 * 768);
    float4* dst = (float4*)&xs[0][0];
    for (int t = tid; t < 1536; t += 256) dst[t] = src[t];
  }
  __syncthreads();
  const int sp = tid >> 5;
  const int hb = tid & 31;
  float a[5] = {0.f,0.f,0.f,0.f,0.f};
  const float4* xv = (const float4*)&xs[sp][0];
  for (int e4 = 0; e4 < 192; ++e4) {
    float4 x = xv[e4];
#pragma unroll
    for (int k = 0; k < 5; ++k) {
      int h = hb + 32*k;
      float4 w = ((const float4*)(W1T + h*768))[e4];
      a[k] += x.x*w.x + x.y*w.y + x.z*w.z + x.w*w.w;
    }
  }
#pragma unroll
  for (int k = 0; k < 5; ++k) {
    int h = hb + 32*k;
    if (h < 150) h1s[sp][h] = fmaxf(a[k] + b1[h], 0.f);
    else if (h < 152) h1s[sp][h] = 0.f;
  }
  __syncthreads();
  float a2[5] = {0.f,0.f,0.f,0.f,0.f};
  const float4* hv = (const float4*)&h1s[sp][0];
  for (int e4 = 0; e4 < 38; ++e4) {
    float4 x = hv[e4];
#pragma unroll
    for (int k = 0; k < 5; ++k) {
      int h = hb + 32*k;
      float4 w = ((const float4*)(W2T + h*152))[e4];
      a2[k] += x.x*w.x + x.y*w.y + x.z*w.z + x.w*w.w;
    }
  }
#pragma unroll
  for (int k = 0; k < 5; ++k) {
    int h = hb + 32*k;
    if (h < 150) h2s[sp][h] = fmaxf(a2[k] + b2[h], 0.f);
    else if (h < 152) h2s[sp][h] = 0.f;
  }
  __syncthreads();
  float p = 0.f;
#pragma unroll
  for (int k = 0; k < 5; ++k) {
    int h = hb + 32*k;
    if (h < 150) p += h2s[sp][h] * w3[h];
  }
  p += __shfl_xor(p, 16, 32);
  p += __shfl_xor(p, 8, 32);
  p += __shfl_xor(p, 4, 32);
  p += __shfl_xor(p, 2, 32);
  p += __shfl_xor(p, 1, 32);
  if (hb == 0) attn[t0 + sp] = p + b3[0];
}

// ---------------------------------------------------------------------------
// g[s] = [e[start], e[end], sum_{t=start..end} e[t]*attn[t]]  (width < 16)
// ---------------------------------------------------------------------------
__global__ __launch_bounds__(256) void k_spans(
    const float* __restrict__ e, const float* __restrict__ attn,
    const int* __restrict__ sstart, const int* __restrict__ swidth,
    float* __restrict__ g) {
  const int s = blockIdx.x;
  int st = sstart[s];
  int en = st + swidth[s];
  if (en > 2047) en = 2047;
  if (en < 0) en = 0;
  const int tid = threadIdx.x;
  for (int d = tid; d < 768; d += 256) {
    g[s*2304 + d]       = e[(size_t)st*768 + d];
    g[s*2304 + 768 + d] = e[(size_t)en*768 + d];
    float acc = 0.f;
    for (int t = st; t <= en; ++t) acc += e[(size_t)t*768 + d] * attn[t];
    g[s*2304 + 1536 + d] = acc;
  }
}

// ---------------------------------------------------------------------------
// m-MLP + hi + hj. 2 spans per block, 128 blocks. fp32.
// hi/hj stored zero-padded to 160 cols.
// ---------------------------------------------------------------------------
__global__ __launch_bounds__(256) void k_spanmlp(
    const float* __restrict__ g, const float* __restrict__ mW1T,
    const float* __restrict__ WaT, const float* __restrict__ WbT,
    const float* __restrict__ mW2T,
    const float* __restrict__ b1, const float* __restrict__ b2,
    const float* __restrict__ w3, const float* __restrict__ b3,
    float* __restrict__ hi, float* __restrict__ hj, float* __restrict__ mo) {
  __shared__ float gs[2][2304];
  __shared__ float h1s[2][152];
  __shared__ float h2s[2][152];
  __shared__ float red[256];
  const int tid = threadIdx.x;
  const int s0 = blockIdx.x * 2;
  {
    const float4* src = (const float4*)(g + (size_t)s0*2304);
    float4* dst = (float4*)&gs[0][0];
    for (int t = tid; t < 1152; t += 256) dst[t] = src[t];
  }
  __syncthreads();
  const int sp = tid >> 7;
  const int hb = tid & 127;
  float am[2] = {0.f,0.f}, aa[2] = {0.f,0.f}, ab[2] = {0.f,0.f};
  const float4* xv = (const float4*)&gs[sp][0];
  for (int e4 = 0; e4 < 576; ++e4) {
    float4 x = xv[e4];
#pragma unroll
    for (int k = 0; k < 2; ++k) {
      int h = hb + 128*k;
      if (h < 160) {
        float4 w = ((const float4*)(mW1T + h*2304))[e4];
        am[k] += x.x*w.x + x.y*w.y + x.z*w.z + x.w*w.w;
        w = ((const float4*)(WaT + h*2304))[e4];
        aa[k] += x.x*w.x + x.y*w.y + x.z*w.z + x.w*w.w;
        w = ((const float4*)(WbT + h*2304))[e4];
        ab[k] += x.x*w.x + x.y*w.y + x.z*w.z + x.w*w.w;
      }
    }
  }
#pragma unroll
  for (int k = 0; k < 2; ++k) {
    int h = hb + 128*k;
    if (h < 160) {
      hi[(s0+sp)*160 + h] = aa[k];
      hj[(s0+sp)*160 + h] = ab[k];
      if (h < 150) h1s[sp][h] = fmaxf(am[k] + b1[h], 0.f);
      else if (h < 152) h1s[sp][h] = 0.f;
    }
  }
  __syncthreads();
  float a2[2] = {0.f,0.f};
  const float4* hv = (const float4*)&h1s[sp][0];
  for (int e4 = 0; e4 < 38; ++e4) {
    float4 x = hv[e4];
#pragma unroll
    for (int k = 0; k < 2; ++k) {
      int h = hb + 128*k;
      if (h < 160) {
        float4 w = ((const float4*)(mW2T + h*152))[e4];
        a2[k] += x.x*w.x + x.y*w.y + x.z*w.z + x.w*w.w;
      }
    }
  }
#pragma unroll
  for (int k = 0; k < 2; ++k) {
    int h = hb + 128*k;
    if (h < 150) h2s[sp][h] = fmaxf(a2[k] + b2[h], 0.f);
    else if (h >= 150 && h < 152) h2s[sp][h] = 0.f;
  }
  __syncthreads();
  float p = 0.f;
#pragma unroll
  for (int k = 0; k < 2; ++k) {
    int h = hb + 128*k;
    if (h < 150) p += h2s[sp][h] * w3[h];
  }
  red[tid] = p;
  __syncthreads();
  if (tid < 2) {
    float sm = 0.f;
    for (int q = 0; q < 128; ++q) sm += red[tid*128 + q];
    mo[s0 + tid] = sm + b3[0];
  }
}

// ---------------------------------------------------------------------------
// Big einsum + h1 epilogue (MFMA bf16):
//   block (jt, i): h1[i, j0..j0+63, 0..159] =
//     relu( (g .* g[i]) @ Wc  + hi[i] + hj[j] + pb1 )   -> bf16
// 4 waves as (wj in {0,1}) x (wh in {0,1}); wave tile 32j x 80h.
// LDS rows are 128B -> XOR swizzle ((row&7)<<4) is bijective & conflict-free.
// ---------------------------------------------------------------------------
__global__ __launch_bounds__(256) void k_hij(
    const float* __restrict__ g, const u16* __restrict__ WcT,
    const float* __restrict__ hi, const float* __restrict__ hj,
    const float* __restrict__ pb1, u16* __restrict__ h1out) {
  __shared__ float gi[2304];
  __shared__ u16 lA[64*64];
  __shared__ u16 lB[160*64];
  const int tid  = threadIdx.x;
  const int lane = tid & 63;
  const int w    = tid >> 6;
  const int wj   = w & 1, wh = w >> 1;
  const int i  = blockIdx.y;
  const int j0 = blockIdx.x * 64;

  {
    const float4* src = (const float4*)(g + (size_t)i*2304);
    float4* dst = (float4*)gi;
    for (int t = tid; t < 576; t += 256) dst[t] = src[t];
  }
  f32x4 acc[2][5] = {};
  __syncthreads();

  for (int e0 = 0; e0 < 2304; e0 += 64) {
    // stage A' = g[j,:] * g[i,:]  (scaled on the fly, fp32 -> bf16)
#pragma unroll
    for (int t = 0; t < 2; ++t) {
      int c = tid + t*256;
      int j = c >> 3, ec = c & 7;
      const float* gr = g + (size_t)(j0 + j)*2304 + e0 + ec*8;
      float4 x0 = *(const float4*)gr;
      float4 x1 = *(const float4*)(gr + 4);
      const float* gp = gi + e0 + ec*8;
      u32 p0 = (u32)f2bf(x0.x*gp[0]) | ((u32)f2bf(x0.y*gp[1]) << 16);
      u32 p1 = (u32)f2bf(x0.z*gp[2]) | ((u32)f2bf(x0.w*gp[3]) << 16);
      u32 p2 = (u32)f2bf(x1.x*gp[4]) | ((u32)f2bf(x1.y*gp[5]) << 16);
      u32 p3 = (u32)f2bf(x1.z*gp[6]) | ((u32)f2bf(x1.w*gp[7]) << 16);
      int off = (j*128 + ec*16) ^ ((j & 7) << 4);
      *(uint4*)((char*)lA + off) = make_uint4(p0, p1, p2, p3);
    }
    // stage B^T chunk (WcT rows = h, cols = e)
#pragma unroll
    for (int t = 0; t < 5; ++t) {
      int c = tid + t*256;
      int h = c >> 3, ec = c & 7;
      uint4 v = *(const uint4*)(WcT + (size_t)h*2304 + e0 + ec*8);
      int off = (h*128 + ec*16) ^ ((h & 7) << 4);
      *(uint4*)((char*)lB + off) = v;
    }
    __syncthreads();
#pragma unroll
    for (int ks = 0; ks < 2; ++ks) {
      const int eb = ks*64 + ((lane >> 4) << 4);
      bf16x8 af[2], bfr[5];
#pragma unroll
      for (int q = 0; q < 2; ++q) {
        int row = wj*32 + q*16 + (lane & 15);
        af[q] = *(const bf16x8*)((const char*)lA + ((row*128 + eb) ^ ((row & 7) << 4)));
      }
#pragma unroll
      for (int t = 0; t < 5; ++t) {
        int row = wh*80 + t*16 + (lane & 15);
        bfr[t] = *(const bf16x8*)((const char*)lB + ((row*128 + eb) ^ ((row & 7) << 4)));
      }
#pragma unroll
      for (int q = 0; q < 2; ++q)
#pragma unroll
        for (int t = 0; t < 5; ++t)
          acc[q][t] = __builtin_amdgcn_mfma_f32_16x16x32_bf16(af[q], bfr[t], acc[q][t], 0, 0, 0);
    }
    __syncthreads();
  }
  // epilogue: + hi[i] + hj[j] + pb1, relu, bf16 store
#pragma unroll
  for (int t = 0; t < 5; ++t) {
    int h = wh*80 + t*16 + (lane & 15);
    float hib = hi[i*160 + h] + ((h < 150) ? pb1[h] : 0.f);
#pragma unroll
    for (int q = 0; q < 2; ++q) {
      int jbase = j0 + wj*32 + q*16 + ((lane >> 4) << 2);
#pragma unroll
      for (int r = 0; r < 4; ++r) {
        int j = jbase + r;
        float v = acc[q][t][r] + hib + hj[j*160 + h];
        v = fmaxf(v, 0.f);
        h1out[(size_t)(i*256 + j)*160 + h] = f2bf(v);
      }
    }
  }
}

// ---------------------------------------------------------------------------
// Final: h2 = relu(h1 @ pW2 + pb2); s = h2 . pW3 + pb3;
//        out = clip((m[i]+m[j]+s)/3, 0, 1).
// 32 rows (=i*256+j pairs) per block, 2048 blocks. MFMA, K = 160 (padded).
// LDS rows padded to 336B (21*16B, odd*16 -> conflict-free, bijective).
// ---------------------------------------------------------------------------
__global__ __launch_bounds__(256) void k_final(
    const u16* __restrict__ h1, const u16* __restrict__ W2T,
    const float* __restrict__ b2, const float* __restrict__ w3,
    const float* __restrict__ b3, const float* __restrict__ mv,
    float* __restrict__ out) {
  __shared__ u16 lH[32*168];    // stride 168 elems = 336B
  __shared__ u16 lW[160*168];
  __shared__ float red2[32][2];
  const int tid  = threadIdx.x;
  const int lane = tid & 63;
  const int w    = tid >> 6;
  const int wm   = w & 1, wh = w >> 1;
  const int M0   = blockIdx.x * 32;

  for (int t = tid; t < 640; t += 256) {
    int r = t / 20, kc = t % 20;
    uint4 v = *(const uint4*)(h1 + (size_t)(M0 + r)*160 + kc*8);
    *(uint4*)((char*)lH + r*336 + kc*16) = v;
  }
  for (int t = tid; t < 3200; t += 256) {
    int r = t / 20, kc = t % 20;
    uint4 v = *(const uint4*)(W2T + (size_t)r*160 + kc*8);
    *(uint4*)((char*)lW + r*336 + kc*16) = v;
  }
  __syncthreads();

  f32x4 acc[5] = {};
#pragma unroll
  for (int ks = 0; ks < 5; ++ks) {
    int kb = ks*64 + ((lane >> 4) << 4);
    int ar = wm*16 + (lane & 15);
    bf16x8 a = *(const bf16x8*)((const char*)lH + ar*336 + kb);
#pragma unroll
    for (int t = 0; t < 5; ++t) {
      int br = wh*80 + t*16 + (lane & 15);
      bf16x8 b = *(const bf16x8*)((const char*)lW + br*336 + kb);
      acc[t] = __builtin_amdgcn_mfma_f32_16x16x32_bf16(a, b, acc[t], 0, 0, 0);
    }
  }
  float part[4] = {0.f,0.f,0.f,0.f};
#pragma unroll
  for (int t = 0; t < 5; ++t) {
    int h = wh*80 + t*16 + (lane & 15);
    float bb = (h < 150) ? b2[h] : 0.f;
    float ww = (h < 150) ? w3[h] : 0.f;
#pragma unroll
    for (int r = 0; r < 4; ++r) {
      float v = fmaxf(acc[t][r] + bb, 0.f);
      part[r] += v * ww;
    }
  }
#pragma unroll
  for (int r = 0; r < 4; ++r) {
    part[r] += __shfl_xor(part[r], 1, 16);
    part[r] += __shfl_xor(part[r], 2, 16);
    part[r] += __shfl_xor(part[r], 4, 16);
    part[r] += __shfl_xor(part[r], 8, 16);
  }
  if ((lane & 15) == 0) {
#pragma unroll
    for (int r = 0; r < 4; ++r)
      red2[wm*16 + ((lane >> 4) << 2) + r][wh] = part[r];
  }
  __syncthreads();
  if (tid < 32) {
    int M = M0 + tid;
    float s = red2[tid][0] + red2[tid][1] + b3[0];
    int i = M >> 8, j = M & 255;
    float v = (mv[i] + mv[j] + s) * (1.f / 3.f);
    v = fminf(fmaxf(v, 0.f), 1.f);
    out[M] = v;
  }
}

// ---------------------------------------------------------------------------
extern "C" void kernel_launch(void* const* d_in, const int* in_sizes, int n_in,
                              void* d_out, int out_size, void* d_ws, size_t ws_size,
                              hipStream_t stream) {
  (void)in_sizes; (void)n_in; (void)out_size; (void)ws_size;
  const float* e    = (const float*)d_in[0];
  const int*   sst  = (const int*)d_in[1];
  const int*   swd  = (const int*)d_in[2];
  const float* aW1  = (const float*)d_in[3];
  const float* ab1  = (const float*)d_in[4];
  const float* aW2  = (const float*)d_in[5];
  const float* ab2  = (const float*)d_in[6];
  const float* aW3  = (const float*)d_in[7];
  const float* ab3  = (const float*)d_in[8];
  const float* mW1  = (const float*)d_in[9];
  const float* mb1  = (const float*)d_in[10];
  const float* mW2  = (const float*)d_in[11];
  const float* mb2  = (const float*)d_in[12];
  const float* mW3  = (const float*)d_in[13];
  const float* mb3  = (const float*)d_in[14];
  const float* pW1  = (const float*)d_in[15];
  const float* pb1  = (const float*)d_in[16];
  const float* pW2  = (const float*)d_in[17];
  const float* pb2  = (const float*)d_in[18];
  const float* pW3  = (const float*)d_in[19];
  const float* pb3  = (const float*)d_in[20];
  float* out = (float*)d_out;

  char* ws = (char*)d_ws;
  size_t off = 0;
  auto alloc = [&](size_t bytes) -> char* {
    char* p = ws + off;
    off += (bytes + 255) & ~(size_t)255;
    return p;
  };
  float* attn  = (float*)alloc(2048ULL*4);
  float* g     = (float*)alloc(256ULL*2304*4);
  float* hi    = (float*)alloc(256ULL*160*4);
  float* hj    = (float*)alloc(256ULL*160*4);
  float* mv    = (float*)alloc(256ULL*4);
  float* W1aT  = (float*)alloc(160ULL*768*4);
  float* W2aT  = (float*)alloc(160ULL*152*4);
  float* mW1T  = (float*)alloc(160ULL*2304*4);
  float* WaT   = (float*)alloc(160ULL*2304*4);
  float* WbT   = (float*)alloc(160ULL*2304*4);
  float* mW2T  = (float*)alloc(160ULL*152*4);
  u16*   WcT   = (u16*)alloc(160ULL*2304*2);
  u16*   W2pT  = (u16*)alloc(160ULL*160*2);
  u16*   h1    = (u16*)alloc(65536ULL*160*2);

  k_prep<<<1024, 256, 0, stream>>>(aW1, aW2, mW1, mW2, pW1, pW2,
                                   W1aT, W2aT, mW1T, WaT, WbT, mW2T, WcT, W2pT);
  k_attn<<<256, 256, 0, stream>>>(e, W1aT, ab1, W2aT, ab2, aW3, ab3, attn);
  k_spans<<<256, 256, 0, stream>>>(e, attn, sst, swd, g);
  k_spanmlp<<<128, 256, 0, stream>>>(g, mW1T, WaT, WbT, mW2T,
                                     mb1, mb2, mW3, mb3, hi, hj, mv);
  k_hij<<<dim3(4, 256), 256, 0, stream>>>(g, WcT, hi, hj, pb1, h1);
  k_final<<<2048, 256, 0, stream>>>(h1, W2pT, pb2, pW3, pb3, mv, out);
}

// Round 2
// 227.315 us; speedup vs baseline: 2.8386x; 2.8386x over previous
//
#include <hip/hip_runtime.h>

typedef unsigned short u16;
typedef unsigned int   u32;
typedef short bf16x8 __attribute__((ext_vector_type(8)));
typedef float f32x4  __attribute__((ext_vector_type(4)));

__device__ __forceinline__ u16 f2bf(float f) {
  union { float f; u32 u; } v; v.f = f;
  u32 u = v.u;
  u += 0x7fffu + ((u >> 16) & 1u);   // RNE
  return (u16)(u >> 16);
}

__device__ __forceinline__ void splitbf(float x, u16& hi, u16& lo) {
  hi = f2bf(x);
  union { u32 u; float f; } r; r.u = (u32)hi << 16;
  lo = f2bf(x - r.f);
}

// ---------------------------------------------------------------------------
// Prep: padded / transposed / bf16-split weight layouts.
//  aW1Th/l [160][768] bf16 (aW1^T split)
//  Wcath/l [480][2304] bf16 ( [mW1 | pW1a | pW1b]^T split )
//  aW2p/mW2p [152][160] f32 k-major (row k, col h; zero-padded)
//  WcT [160][2304] bf16 (pW1 rows 4608.., ^T)   W2pT [160][160] bf16 (pW2^T)
// ---------------------------------------------------------------------------
__global__ __launch_bounds__(256) void k_prep(
    const float* __restrict__ aW1, const float* __restrict__ mW1,
    const float* __restrict__ pW1, const float* __restrict__ aW2,
    const float* __restrict__ mW2, const float* __restrict__ pW2,
    u16* __restrict__ aW1Th, u16* __restrict__ aW1Tl,
    u16* __restrict__ Wcath, u16* __restrict__ Wcatl,
    float* __restrict__ aW2p, float* __restrict__ mW2p,
    u16* __restrict__ WcT, u16* __restrict__ W2pT) {
  const int stride = gridDim.x * blockDim.x;
  const int t0 = blockIdx.x * blockDim.x + threadIdx.x;
  for (int t = t0; t < 160*768; t += stride) {
    int h = t / 768, e = t % 768;
    float v = (h < 150) ? aW1[e*150 + h] : 0.f;
    splitbf(v, aW1Th[t], aW1Tl[t]);
  }
  for (int t = t0; t < 480*2304; t += stride) {
    int n = t / 2304, e = t % 2304;
    float v;
    if (n < 160)      v = (n < 150) ? mW1[e*150 + n] : 0.f;
    else if (n < 320) { int h = n-160; v = (h < 150) ? pW1[(size_t)e*150 + h] : 0.f; }
    else              { int h = n-320; v = (h < 150) ? pW1[(size_t)(2304+e)*150 + h] : 0.f; }
    splitbf(v, Wcath[t], Wcatl[t]);
  }
  for (int t = t0; t < 152*160; t += stride) {
    int k = t / 160, h = t % 160;
    bool ok = (k < 150 && h < 150);
    aW2p[t] = ok ? aW2[k*150 + h] : 0.f;
    mW2p[t] = ok ? mW2[k*150 + h] : 0.f;
  }
  for (int t = t0; t < 160*2304; t += stride) {
    int h = t / 2304, e = t % 2304;
    WcT[t] = (h < 150) ? f2bf(pW1[(size_t)(4608 + e)*150 + h]) : (u16)0;
  }
  for (int t = t0; t < 160*160; t += stride) {
    int h2 = t / 160, h1 = t % 160;
    W2pT[t] = (h2 < 150 && h1 < 150) ? f2bf(pW2[h1*150 + h2]) : (u16)0;
  }
}

// ---------------------------------------------------------------------------
// attn layer1 (split-bf16 MFMA GEMM): h1a[2048][152] = relu(e @ aW1 + ab1)
// block tile 32M x 160N, 4 waves (wm x wh), wave 16x80. K=768, chunk 64.
// ---------------------------------------------------------------------------
__global__ __launch_bounds__(256) void k_attn1(
    const float* __restrict__ e, const u16* __restrict__ Wh,
    const u16* __restrict__ Wl, const float* __restrict__ b1,
    float* __restrict__ h1a) {
  __shared__ u16 lXh[32*64], lXl[32*64], lWh[160*64], lWl[160*64];
  const int tid = threadIdx.x, lane = tid & 63, w = tid >> 6;
  const int wm = w & 1, wh = w >> 1;
  const int m0 = blockIdx.x * 32;
  f32x4 acc[5] = {};
  for (int e0 = 0; e0 < 768; e0 += 64) {
    {
      int r = tid >> 3, ec = tid & 7;
      const float* src = e + (size_t)(m0 + r)*768 + e0 + ec*8;
      float4 x0 = *(const float4*)src, x1 = *(const float4*)(src + 4);
      float xs[8] = {x0.x,x0.y,x0.z,x0.w,x1.x,x1.y,x1.z,x1.w};
      u16 hb[8], lb[8];
#pragma unroll
      for (int q = 0; q < 8; ++q) splitbf(xs[q], hb[q], lb[q]);
      int off = (r*128 + ec*16) ^ ((r & 7) << 4);
      *(uint4*)((char*)lXh + off) = make_uint4(
        (u32)hb[0]|((u32)hb[1]<<16), (u32)hb[2]|((u32)hb[3]<<16),
        (u32)hb[4]|((u32)hb[5]<<16), (u32)hb[6]|((u32)hb[7]<<16));
      *(uint4*)((char*)lXl + off) = make_uint4(
        (u32)lb[0]|((u32)lb[1]<<16), (u32)lb[2]|((u32)lb[3]<<16),
        (u32)lb[4]|((u32)lb[5]<<16), (u32)lb[6]|((u32)lb[7]<<16));
    }
#pragma unroll
    for (int t = 0; t < 5; ++t) {
      int c = tid + t*256;
      int h = c >> 3, ec = c & 7;
      int off = (h*128 + ec*16) ^ ((h & 7) << 4);
      *(uint4*)((char*)lWh + off) = *(const uint4*)(Wh + (size_t)h*768 + e0 + ec*8);
      *(uint4*)((char*)lWl + off) = *(const uint4*)(Wl + (size_t)h*768 + e0 + ec*8);
    }
    __syncthreads();
#pragma unroll
    for (int ks = 0; ks < 2; ++ks) {
      int eb = ks*64 + ((lane >> 4) << 4);
      int ar = wm*16 + (lane & 15);
      bf16x8 Ah = *(const bf16x8*)((const char*)lXh + ((ar*128 + eb) ^ ((ar & 7) << 4)));
      bf16x8 Al = *(const bf16x8*)((const char*)lXl + ((ar*128 + eb) ^ ((ar & 7) << 4)));
#pragma unroll
      for (int t = 0; t < 5; ++t) {
        int br = wh*80 + t*16 + (lane & 15);
        bf16x8 Bh = *(const bf16x8*)((const char*)lWh + ((br*128 + eb) ^ ((br & 7) << 4)));
        bf16x8 Bl = *(const bf16x8*)((const char*)lWl + ((br*128 + eb) ^ ((br & 7) << 4)));
        acc[t] = __builtin_amdgcn_mfma_f32_16x16x32_bf16(Ah, Bh, acc[t], 0, 0, 0);
        acc[t] = __builtin_amdgcn_mfma_f32_16x16x32_bf16(Al, Bh, acc[t], 0, 0, 0);
        acc[t] = __builtin_amdgcn_mfma_f32_16x16x32_bf16(Ah, Bl, acc[t], 0, 0, 0);
      }
    }
    __syncthreads();
  }
#pragma unroll
  for (int t = 0; t < 5; ++t) {
    int n = wh*80 + t*16 + (lane & 15);
    if (n < 152) {
      float bb = (n < 150) ? b1[n] : 0.f;
#pragma unroll
      for (int r = 0; r < 4; ++r) {
        int m = m0 + wm*16 + ((lane >> 4) << 2) + r;
        float v = acc[t][r] + bb;
        h1a[(size_t)m*152 + n] = (n < 150) ? fmaxf(v, 0.f) : 0.f;
      }
    }
  }
}

// ---------------------------------------------------------------------------
// attn layers 2+3: attn[t] = relu(h1a @ aW2 + b2) . w3 + b3. 8 tokens/block.
// ---------------------------------------------------------------------------
__global__ __launch_bounds__(256) void k_attn2(
    const float* __restrict__ h1a, const float* __restrict__ W2p,
    const float* __restrict__ b2, const float* __restrict__ w3,
    const float* __restrict__ b3, float* __restrict__ attn) {
  __shared__ float hs[8][152];
  const int tid = threadIdx.x;
  const int t0 = blockIdx.x * 8;
  for (int t = tid; t < 304; t += 256)
    ((float4*)&hs[0][0])[t] = ((const float4*)(h1a + (size_t)t0*152))[t];
  __syncthreads();
  const int sp = tid >> 5, hb = tid & 31;
  float a2[5] = {0.f,0.f,0.f,0.f,0.f};
  for (int k = 0; k < 150; ++k) {
    float x = hs[sp][k];
#pragma unroll
    for (int q = 0; q < 5; ++q) a2[q] = fmaf(x, W2p[k*160 + hb + 32*q], a2[q]);
  }
  float p = 0.f;
#pragma unroll
  for (int q = 0; q < 5; ++q) {
    int h = hb + 32*q;
    if (h < 150) p += fmaxf(a2[q] + b2[h], 0.f) * w3[h];
  }
  p += __shfl_xor(p, 16, 32);
  p += __shfl_xor(p, 8, 32);
  p += __shfl_xor(p, 4, 32);
  p += __shfl_xor(p, 2, 32);
  p += __shfl_xor(p, 1, 32);
  if (hb == 0) attn[t0 + sp] = p + b3[0];
}

// ---------------------------------------------------------------------------
// g[s] = [e[start], e[end], sum_{t=start..end} e[t]*attn[t]]  (width < 16)
// ---------------------------------------------------------------------------
__global__ __launch_bounds__(256) void k_spans(
    const float* __restrict__ e, const float* __restrict__ attn,
    const int* __restrict__ sstart, const int* __restrict__ swidth,
    float* __restrict__ g) {
  const int s = blockIdx.x;
  int st = sstart[s];
  int en = st + swidth[s];
  if (en > 2047) en = 2047;
  if (en < 0) en = 0;
  const int tid = threadIdx.x;
  for (int d = tid; d < 768; d += 256) {
    g[s*2304 + d]       = e[(size_t)st*768 + d];
    g[s*2304 + 768 + d] = e[(size_t)en*768 + d];
    float acc = 0.f;
    for (int t = st; t <= en; ++t) acc += e[(size_t)t*768 + d] * attn[t];
    g[s*2304 + 1536 + d] = acc;
  }
}

// ---------------------------------------------------------------------------
// span layer1 (split-bf16 MFMA GEMM): [mh1 | hi | hj] = g @ [mW1|Wa|Wb]
// grid (16 Mtiles, 3 Ntiles), block 128 thr = 2 waves, wave 16M x 80N.
// K=2304, chunk 64.
// ---------------------------------------------------------------------------
__global__ __launch_bounds__(128) void k_span1(
    const float* __restrict__ g, const u16* __restrict__ Wh,
    const u16* __restrict__ Wl, const float* __restrict__ mb1,
    float* __restrict__ mh1, float* __restrict__ hi, float* __restrict__ hj) {
  __shared__ u16 lXh[16*64], lXl[16*64], lWh[160*64], lWl[160*64];
  const int tid = threadIdx.x, lane = tid & 63;
  const int wh = tid >> 6;
  const int m0 = blockIdx.x * 16;
  const int n0 = blockIdx.y * 160;
  f32x4 acc[5] = {};
  for (int e0 = 0; e0 < 2304; e0 += 64) {
    {
      int r = tid >> 3, ec = tid & 7;
      const float* src = g + (size_t)(m0 + r)*2304 + e0 + ec*8;
      float4 x0 = *(const float4*)src, x1 = *(const float4*)(src + 4);
      float xs[8] = {x0.x,x0.y,x0.z,x0.w,x1.x,x1.y,x1.z,x1.w};
      u16 hb[8], lb[8];
#pragma unroll
      for (int q = 0; q < 8; ++q) splitbf(xs[q], hb[q], lb[q]);
      int off = (r*128 + ec*16) ^ ((r & 7) << 4);
      *(uint4*)((char*)lXh + off) = make_uint4(
        (u32)hb[0]|((u32)hb[1]<<16), (u32)hb[2]|((u32)hb[3]<<16),
        (u32)hb[4]|((u32)hb[5]<<16), (u32)hb[6]|((u32)hb[7]<<16));
      *(uint4*)((char*)lXl + off) = make_uint4(
        (u32)lb[0]|((u32)lb[1]<<16), (u32)lb[2]|((u32)lb[3]<<16),
        (u32)lb[4]|((u32)lb[5]<<16), (u32)lb[6]|((u32)lb[7]<<16));
    }
#pragma unroll
    for (int t = 0; t < 10; ++t) {
      int c = tid + t*128;
      int h = c >> 3, ec = c & 7;
      int off = (h*128 + ec*16) ^ ((h & 7) << 4);
      *(uint4*)((char*)lWh + off) = *(const uint4*)(Wh + (size_t)(n0 + h)*2304 + e0 + ec*8);
      *(uint4*)((char*)lWl + off) = *(const uint4*)(Wl + (size_t)(n0 + h)*2304 + e0 + ec*8);
    }
    __syncthreads();
#pragma unroll
    for (int ks = 0; ks < 2; ++ks) {
      int eb = ks*64 + ((lane >> 4) << 4);
      int ar = lane & 15;
      bf16x8 Ah = *(const bf16x8*)((const char*)lXh + ((ar*128 + eb) ^ ((ar & 7) << 4)));
      bf16x8 Al = *(const bf16x8*)((const char*)lXl + ((ar*128 + eb) ^ ((ar & 7) << 4)));
#pragma unroll
      for (int t = 0; t < 5; ++t) {
        int br = wh*80 + t*16 + (lane & 15);
        bf16x8 Bh = *(const bf16x8*)((const char*)lWh + ((br*128 + eb) ^ ((br & 7) << 4)));
        bf16x8 Bl = *(const bf16x8*)((const char*)lWl + ((br*128 + eb) ^ ((br & 7) << 4)));
        acc[t] = __builtin_amdgcn_mfma_f32_16x16x32_bf16(Ah, Bh, acc[t], 0, 0, 0);
        acc[t] = __builtin_amdgcn_mfma_f32_16x16x32_bf16(Al, Bh, acc[t], 0, 0, 0);
        acc[t] = __builtin_amdgcn_mfma_f32_16x16x32_bf16(Ah, Bl, acc[t], 0, 0, 0);
      }
    }
    __syncthreads();
  }
#pragma unroll
  for (int t = 0; t < 5; ++t) {
    int nc = n0 + wh*80 + t*16 + (lane & 15);
#pragma unroll
    for (int r = 0; r < 4; ++r) {
      int m = m0 + ((lane >> 4) << 2) + r;
      float c = acc[t][r];
      if (nc < 160)      mh1[(size_t)m*160 + nc] = (nc < 150) ? fmaxf(c + mb1[nc], 0.f) : 0.f;
      else if (nc < 320) hi[(size_t)m*160 + (nc - 160)] = c;
      else               hj[(size_t)m*160 + (nc - 320)] = c;
    }
  }
}

// ---------------------------------------------------------------------------
// span layers 2+3: mo[s] = relu(mh1 @ mW2 + b2) . w3 + b3. 8 spans/block.
// ---------------------------------------------------------------------------
__global__ __launch_bounds__(256) void k_span2(
    const float* __restrict__ mh1, const float* __restrict__ W2p,
    const float* __restrict__ b2, const float* __restrict__ w3,
    const float* __restrict__ b3, float* __restrict__ mo) {
  __shared__ float hs[8][160];
  const int tid = threadIdx.x;
  const int s0 = blockIdx.x * 8;
  for (int t = tid; t < 320; t += 256)
    ((float4*)&hs[0][0])[t] = ((const float4*)(mh1 + (size_t)s0*160))[t];
  __syncthreads();
  const int sp = tid >> 5, hb = tid & 31;
  float a2[5] = {0.f,0.f,0.f,0.f,0.f};
  for (int k = 0; k < 150; ++k) {
    float x = hs[sp][k];
#pragma unroll
    for (int q = 0; q < 5; ++q) a2[q] = fmaf(x, W2p[k*160 + hb + 32*q], a2[q]);
  }
  float p = 0.f;
#pragma unroll
  for (int q = 0; q < 5; ++q) {
    int h = hb + 32*q;
    if (h < 150) p += fmaxf(a2[q] + b2[h], 0.f) * w3[h];
  }
  p += __shfl_xor(p, 16, 32);
  p += __shfl_xor(p, 8, 32);
  p += __shfl_xor(p, 4, 32);
  p += __shfl_xor(p, 2, 32);
  p += __shfl_xor(p, 1, 32);
  if (hb == 0) mo[s0 + sp] = p + b3[0];
}

// ---------------------------------------------------------------------------
// Big einsum + h1 epilogue (MFMA bf16):
//   block (jt, i): h1[i, j0..j0+63, 0..159] =
//     relu( (g .* g[i]) @ Wc  + hi[i] + hj[j] + pb1 )   -> bf16
// ---------------------------------------------------------------------------
__global__ __launch_bounds__(256) void k_hij(
    const float* __restrict__ g, const u16* __restrict__ WcT,
    const float* __restrict__ hi, const float* __restrict__ hj,
    const float* __restrict__ pb1, u16* __restrict__ h1out) {
  __shared__ float gi[2304];
  __shared__ u16 lA[64*64];
  __shared__ u16 lB[160*64];
  const int tid  = threadIdx.x;
  const int lane = tid & 63;
  const int w    = tid >> 6;
  const int wj   = w & 1, wh = w >> 1;
  const int i  = blockIdx.y;
  const int j0 = blockIdx.x * 64;

  {
    const float4* src = (const float4*)(g + (size_t)i*2304);
    float4* dst = (float4*)gi;
    for (int t = tid; t < 576; t += 256) dst[t] = src[t];
  }
  f32x4 acc[2][5] = {};
  __syncthreads();

  for (int e0 = 0; e0 < 2304; e0 += 64) {
#pragma unroll
    for (int t = 0; t < 2; ++t) {
      int c = tid + t*256;
      int j = c >> 3, ec = c & 7;
      const float* gr = g + (size_t)(j0 + j)*2304 + e0 + ec*8;
      float4 x0 = *(const float4*)gr;
      float4 x1 = *(const float4*)(gr + 4);
      const float* gp = gi + e0 + ec*8;
      u32 p0 = (u32)f2bf(x0.x*gp[0]) | ((u32)f2bf(x0.y*gp[1]) << 16);
      u32 p1 = (u32)f2bf(x0.z*gp[2]) | ((u32)f2bf(x0.w*gp[3]) << 16);
      u32 p2 = (u32)f2bf(x1.x*gp[4]) | ((u32)f2bf(x1.y*gp[5]) << 16);
      u32 p3 = (u32)f2bf(x1.z*gp[6]) | ((u32)f2bf(x1.w*gp[7]) << 16);
      int off = (j*128 + ec*16) ^ ((j & 7) << 4);
      *(uint4*)((char*)lA + off) = make_uint4(p0, p1, p2, p3);
    }
#pragma unroll
    for (int t = 0; t < 5; ++t) {
      int c = tid + t*256;
      int h = c >> 3, ec = c & 7;
      uint4 v = *(const uint4*)(WcT + (size_t)h*2304 + e0 + ec*8);
      int off = (h*128 + ec*16) ^ ((h & 7) << 4);
      *(uint4*)((char*)lB + off) = v;
    }
    __syncthreads();
#pragma unroll
    for (int ks = 0; ks < 2; ++ks) {
      const int eb = ks*64 + ((lane >> 4) << 4);
      bf16x8 af[2], bfr[5];
#pragma unroll
      for (int q = 0; q < 2; ++q) {
        int row = wj*32 + q*16 + (lane & 15);
        af[q] = *(const bf16x8*)((const char*)lA + ((row*128 + eb) ^ ((row & 7) << 4)));
      }
#pragma unroll
      for (int t = 0; t < 5; ++t) {
        int row = wh*80 + t*16 + (lane & 15);
        bfr[t] = *(const bf16x8*)((const char*)lB + ((row*128 + eb) ^ ((row & 7) << 4)));
      }
#pragma unroll
      for (int q = 0; q < 2; ++q)
#pragma unroll
        for (int t = 0; t < 5; ++t)
          acc[q][t] = __builtin_amdgcn_mfma_f32_16x16x32_bf16(af[q], bfr[t], acc[q][t], 0, 0, 0);
    }
    __syncthreads();
  }
#pragma unroll
  for (int t = 0; t < 5; ++t) {
    int h = wh*80 + t*16 + (lane & 15);
    float hib = hi[i*160 + h] + ((h < 150) ? pb1[h] : 0.f);
#pragma unroll
    for (int q = 0; q < 2; ++q) {
      int jbase = j0 + wj*32 + q*16 + ((lane >> 4) << 2);
#pragma unroll
      for (int r = 0; r < 4; ++r) {
        int j = jbase + r;
        float v = acc[q][t][r] + hib + hj[j*160 + h];
        v = fmaxf(v, 0.f);
        h1out[(size_t)(i*256 + j)*160 + h] = f2bf(v);
      }
    }
  }
}

// ---------------------------------------------------------------------------
// Final: h2 = relu(h1 @ pW2 + pb2); s = h2 . pW3 + pb3;
//        out = clip((m[i]+m[j]+s)/3, 0, 1).
// ---------------------------------------------------------------------------
__global__ __launch_bounds__(256) void k_final(
    const u16* __restrict__ h1, const u16* __restrict__ W2T,
    const float* __restrict__ b2, const float* __restrict__ w3,
    const float* __restrict__ b3, const float* __restrict__ mv,
    float* __restrict__ out) {
  __shared__ u16 lH[32*168];
  __shared__ u16 lW[160*168];
  __shared__ float red2[32][2];
  const int tid  = threadIdx.x;
  const int lane = tid & 63;
  const int w    = tid >> 6;
  const int wm   = w & 1, wh = w >> 1;
  const int M0   = blockIdx.x * 32;

  for (int t = tid; t < 640; t += 256) {
    int r = t / 20, kc = t % 20;
    uint4 v = *(const uint4*)(h1 + (size_t)(M0 + r)*160 + kc*8);
    *(uint4*)((char*)lH + r*336 + kc*16) = v;
  }
  for (int t = tid; t < 3200; t += 256) {
    int r = t / 20, kc = t % 20;
    uint4 v = *(const uint4*)(W2T + (size_t)r*160 + kc*8);
    *(uint4*)((char*)lW + r*336 + kc*16) = v;
  }
  __syncthreads();

  f32x4 acc[5] = {};
#pragma unroll
  for (int ks = 0; ks < 5; ++ks) {
    int kb = ks*64 + ((lane >> 4) << 4);
    int ar = wm*16 + (lane & 15);
    bf16x8 a = *(const bf16x8*)((const char*)lH + ar*336 + kb);
#pragma unroll
    for (int t = 0; t < 5; ++t) {
      int br = wh*80 + t*16 + (lane & 15);
      bf16x8 b = *(const bf16x8*)((const char*)lW + br*336 + kb);
      acc[t] = __builtin_amdgcn_mfma_f32_16x16x32_bf16(a, b, acc[t], 0, 0, 0);
    }
  }
  float part[4] = {0.f,0.f,0.f,0.f};
#pragma unroll
  for (int t = 0; t < 5; ++t) {
    int h = wh*80 + t*16 + (lane & 15);
    float bb = (h < 150) ? b2[h] : 0.f;
    float ww = (h < 150) ? w3[h] : 0.f;
#pragma unroll
    for (int r = 0; r < 4; ++r) {
      float v = fmaxf(acc[t][r] + bb, 0.f);
      part[r] += v * ww;
    }
  }
#pragma unroll
  for (int r = 0; r < 4; ++r) {
    part[r] += __shfl_xor(part[r], 1, 16);
    part[r] += __shfl_xor(part[r], 2, 16);
    part[r] += __shfl_xor(part[r], 4, 16);
    part[r] += __shfl_xor(part[r], 8, 16);
  }
  if ((lane & 15) == 0) {
#pragma unroll
    for (int r = 0; r < 4; ++r)
      red2[wm*16 + ((lane >> 4) << 2) + r][wh] = part[r];
  }
  __syncthreads();
  if (tid < 32) {
    int M = M0 + tid;
    float s = red2[tid][0] + red2[tid][1] + b3[0];
    int i = M >> 8, j = M & 255;
    float v = (mv[i] + mv[j] + s) * (1.f / 3.f);
    v = fminf(fmaxf(v, 0.f), 1.f);
    out[M] = v;
  }
}

// ---------------------------------------------------------------------------
extern "C" void kernel_launch(void* const* d_in, const int* in_sizes, int n_in,
                              void* d_out, int out_size, void* d_ws, size_t ws_size,
                              hipStream_t stream) {
  (void)in_sizes; (void)n_in; (void)out_size; (void)ws_size;
  const float* e    = (const float*)d_in[0];
  const int*   sst  = (const int*)d_in[1];
  const int*   swd  = (const int*)d_in[2];
  const float* aW1  = (const float*)d_in[3];
  const float* ab1  = (const float*)d_in[4];
  const float* aW2  = (const float*)d_in[5];
  const float* ab2  = (const float*)d_in[6];
  const float* aW3  = (const float*)d_in[7];
  const float* ab3  = (const float*)d_in[8];
  const float* mW1  = (const float*)d_in[9];
  const float* mb1  = (const float*)d_in[10];
  const float* mW2  = (const float*)d_in[11];
  const float* mb2  = (const float*)d_in[12];
  const float* mW3  = (const float*)d_in[13];
  const float* mb3  = (const float*)d_in[14];
  const float* pW1  = (const float*)d_in[15];
  const float* pb1  = (const float*)d_in[16];
  const float* pW2  = (const float*)d_in[17];
  const float* pb2  = (const float*)d_in[18];
  const float* pW3  = (const float*)d_in[19];
  const float* pb3  = (const float*)d_in[20];
  float* out = (float*)d_out;

  char* ws = (char*)d_ws;
  size_t off = 0;
  auto alloc = [&](size_t bytes) -> char* {
    char* p = ws + off;
    off += (bytes + 255) & ~(size_t)255;
    return p;
  };
  float* attn  = (float*)alloc(2048ULL*4);
  float* g     = (float*)alloc(256ULL*2304*4);
  float* hi    = (float*)alloc(256ULL*160*4);
  float* hj    = (float*)alloc(256ULL*160*4);
  float* mv    = (float*)alloc(256ULL*4);
  float* h1a   = (float*)alloc(2048ULL*152*4);
  float* mh1   = (float*)alloc(256ULL*160*4);
  u16*   aW1Th = (u16*)alloc(160ULL*768*2);
  u16*   aW1Tl = (u16*)alloc(160ULL*768*2);
  u16*   Wcath = (u16*)alloc(480ULL*2304*2);
  u16*   Wcatl = (u16*)alloc(480ULL*2304*2);
  float* aW2p  = (float*)alloc(152ULL*160*4);
  float* mW2p  = (float*)alloc(152ULL*160*4);
  u16*   WcT   = (u16*)alloc(160ULL*2304*2);
  u16*   W2pT  = (u16*)alloc(160ULL*160*2);
  u16*   h1    = (u16*)alloc(65536ULL*160*2);

  k_prep<<<1024, 256, 0, stream>>>(aW1, mW1, pW1, aW2, mW2, pW2,
                                   aW1Th, aW1Tl, Wcath, Wcatl, aW2p, mW2p, WcT, W2pT);
  k_attn1<<<64, 256, 0, stream>>>(e, aW1Th, aW1Tl, ab1, h1a);
  k_attn2<<<256, 256, 0, stream>>>(h1a, aW2p, ab2, aW3, ab3, attn);
  k_spans<<<256, 256, 0, stream>>>(e, attn, sst, swd, g);
  k_span1<<<dim3(16, 3), 128, 0, stream>>>(g, Wcath, Wcatl, mb1, mh1, hi, hj);
  k_span2<<<32, 256, 0, stream>>>(mh1, mW2p, mb2, mW3, mb3, mv);
  k_hij<<<dim3(4, 256), 256, 0, stream>>>(g, WcT, hi, hj, pb1, h1);
  k_final<<<2048, 256, 0, stream>>>(h1, W2pT, pb2, pW3, pb3, mv, out);
}

// Round 3
// 207.570 us; speedup vs baseline: 3.1086x; 1.0951x over previous
//
#include <hip/hip_runtime.h>

typedef unsigned short u16;
typedef unsigned int   u32;
typedef short bf16x8 __attribute__((ext_vector_type(8)));
typedef float f32x4  __attribute__((ext_vector_type(4)));

__device__ __forceinline__ u16 f2bf(float f) {
  union { float f; u32 u; } v; v.f = f;
  u32 u = v.u;
  u += 0x7fffu + ((u >> 16) & 1u);   // RNE
  return (u16)(u >> 16);
}

__device__ __forceinline__ void splitbf(float x, u16& hi, u16& lo) {
  hi = f2bf(x);
  union { u32 u; float f; } r; r.u = (u32)hi << 16;
  lo = f2bf(x - r.f);
}

__device__ __forceinline__ float bflo(u32 p) {
  union { u32 u; float f; } v; v.u = p << 16; return v.f;
}
__device__ __forceinline__ float bfhi(u32 p) {
  union { u32 u; float f; } v; v.u = p & 0xffff0000u; return v.f;
}
// packed f32x2 -> bf16x2 (RNE), hardware cvt
__device__ __forceinline__ u32 cvtpk(float lo, float hi) {
  u32 r;
  asm("v_cvt_pk_bf16_f32 %0, %1, %2" : "=v"(r) : "v"(lo), "v"(hi));
  return r;
}
// async global->LDS, 16B per lane; dst must be wave-uniform, src per-lane
__device__ __forceinline__ void gload_lds16(const void* src, void* dst) {
  __builtin_amdgcn_global_load_lds(
      (const __attribute__((address_space(1))) u32*)src,
      (__attribute__((address_space(3))) u32*)dst, 16, 0, 0);
}

// ---------------------------------------------------------------------------
// Prep: padded / transposed / bf16-split / k-grouped weight layouts.
//  aW1Th/l [160][768] bf16 (aW1^T split)     Wcath/l [480][2304] bf16
//  aW2p/mW2p [152][160] f32 k-major
//  Wckg [288 grp][160 h][8] bf16  : Wckg[grp][h][s] = pW1[(4608+grp*8+s)*150+h]
//  W2kg [20 grp][160 n][8]  bf16  : W2kg[kg][n][s]  = pW2[(kg*8+s)*150+n]
//  pb1p/pb2p/w3p [160] f32 zero-padded
// ---------------------------------------------------------------------------
__global__ __launch_bounds__(256) void k_prep(
    const float* __restrict__ aW1, const float* __restrict__ mW1,
    const float* __restrict__ pW1, const float* __restrict__ aW2,
    const float* __restrict__ mW2, const float* __restrict__ pW2,
    const float* __restrict__ pb1, const float* __restrict__ pb2,
    const float* __restrict__ pW3,
    u16* __restrict__ aW1Th, u16* __restrict__ aW1Tl,
    u16* __restrict__ Wcath, u16* __restrict__ Wcatl,
    float* __restrict__ aW2p, float* __restrict__ mW2p,
    u16* __restrict__ Wckg, u16* __restrict__ W2kg,
    float* __restrict__ pb1p, float* __restrict__ pb2p,
    float* __restrict__ w3p) {
  const int stride = gridDim.x * blockDim.x;
  const int t0 = blockIdx.x * blockDim.x + threadIdx.x;
  for (int t = t0; t < 160*768; t += stride) {
    int h = t / 768, e = t % 768;
    float v = (h < 150) ? aW1[e*150 + h] : 0.f;
    splitbf(v, aW1Th[t], aW1Tl[t]);
  }
  for (int t = t0; t < 480*2304; t += stride) {
    int n = t / 2304, e = t % 2304;
    float v;
    if (n < 160)      v = (n < 150) ? mW1[e*150 + n] : 0.f;
    else if (n < 320) { int h = n-160; v = (h < 150) ? pW1[(size_t)e*150 + h] : 0.f; }
    else              { int h = n-320; v = (h < 150) ? pW1[(size_t)(2304+e)*150 + h] : 0.f; }
    splitbf(v, Wcath[t], Wcatl[t]);
  }
  for (int t = t0; t < 152*160; t += stride) {
    int k = t / 160, h = t % 160;
    bool ok = (k < 150 && h < 150);
    aW2p[t] = ok ? aW2[k*150 + h] : 0.f;
    mW2p[t] = ok ? mW2[k*150 + h] : 0.f;
  }
  for (int t = t0; t < 288*1280; t += stride) {
    int grp = t / 1280, rem = t % 1280;
    int s = rem / 160, h = rem % 160;
    float v = (h < 150) ? pW1[(size_t)(4608 + grp*8 + s)*150 + h] : 0.f;
    Wckg[(size_t)grp*1280 + h*8 + s] = f2bf(v);
  }
  for (int t = t0; t < 20*1280; t += stride) {
    int kg = t / 1280, rem = t % 1280;
    int s = rem / 160, n = rem % 160;
    int k = kg*8 + s;
    float v = (k < 150 && n < 150) ? pW2[k*150 + n] : 0.f;
    W2kg[(size_t)kg*1280 + n*8 + s] = f2bf(v);
  }
  for (int t = t0; t < 160; t += stride) {
    pb1p[t] = (t < 150) ? pb1[t] : 0.f;
    pb2p[t] = (t < 150) ? pb2[t] : 0.f;
    w3p[t]  = (t < 150) ? pW3[t] : 0.f;
  }
}

// ---------------------------------------------------------------------------
// attn layer1 (split-bf16 MFMA GEMM): h1a[2048][152] = relu(e @ aW1 + ab1)
// ---------------------------------------------------------------------------
__global__ __launch_bounds__(256) void k_attn1(
    const float* __restrict__ e, const u16* __restrict__ Wh,
    const u16* __restrict__ Wl, const float* __restrict__ b1,
    float* __restrict__ h1a) {
  __shared__ u16 lXh[32*64], lXl[32*64], lWh[160*64], lWl[160*64];
  const int tid = threadIdx.x, lane = tid & 63, w = tid >> 6;
  const int wm = w & 1, wh = w >> 1;
  const int m0 = blockIdx.x * 32;
  f32x4 acc[5] = {};
  for (int e0 = 0; e0 < 768; e0 += 64) {
    {
      int r = tid >> 3, ec = tid & 7;
      const float* src = e + (size_t)(m0 + r)*768 + e0 + ec*8;
      float4 x0 = *(const float4*)src, x1 = *(const float4*)(src + 4);
      float xs[8] = {x0.x,x0.y,x0.z,x0.w,x1.x,x1.y,x1.z,x1.w};
      u16 hb[8], lb[8];
#pragma unroll
      for (int q = 0; q < 8; ++q) splitbf(xs[q], hb[q], lb[q]);
      int off = (r*128 + ec*16) ^ ((r & 7) << 4);
      *(uint4*)((char*)lXh + off) = make_uint4(
        (u32)hb[0]|((u32)hb[1]<<16), (u32)hb[2]|((u32)hb[3]<<16),
        (u32)hb[4]|((u32)hb[5]<<16), (u32)hb[6]|((u32)hb[7]<<16));
      *(uint4*)((char*)lXl + off) = make_uint4(
        (u32)lb[0]|((u32)lb[1]<<16), (u32)lb[2]|((u32)lb[3]<<16),
        (u32)lb[4]|((u32)lb[5]<<16), (u32)lb[6]|((u32)lb[7]<<16));
    }
#pragma unroll
    for (int t = 0; t < 5; ++t) {
      int c = tid + t*256;
      int h = c >> 3, ec = c & 7;
      int off = (h*128 + ec*16) ^ ((h & 7) << 4);
      *(uint4*)((char*)lWh + off) = *(const uint4*)(Wh + (size_t)h*768 + e0 + ec*8);
      *(uint4*)((char*)lWl + off) = *(const uint4*)(Wl + (size_t)h*768 + e0 + ec*8);
    }
    __syncthreads();
#pragma unroll
    for (int ks = 0; ks < 2; ++ks) {
      int eb = ks*64 + ((lane >> 4) << 4);
      int ar = wm*16 + (lane & 15);
      bf16x8 Ah = *(const bf16x8*)((const char*)lXh + ((ar*128 + eb) ^ ((ar & 7) << 4)));
      bf16x8 Al = *(const bf16x8*)((const char*)lXl + ((ar*128 + eb) ^ ((ar & 7) << 4)));
#pragma unroll
      for (int t = 0; t < 5; ++t) {
        int br = wh*80 + t*16 + (lane & 15);
        bf16x8 Bh = *(const bf16x8*)((const char*)lWh + ((br*128 + eb) ^ ((br & 7) << 4)));
        bf16x8 Bl = *(const bf16x8*)((const char*)lWl + ((br*128 + eb) ^ ((br & 7) << 4)));
        acc[t] = __builtin_amdgcn_mfma_f32_16x16x32_bf16(Ah, Bh, acc[t], 0, 0, 0);
        acc[t] = __builtin_amdgcn_mfma_f32_16x16x32_bf16(Al, Bh, acc[t], 0, 0, 0);
        acc[t] = __builtin_amdgcn_mfma_f32_16x16x32_bf16(Ah, Bl, acc[t], 0, 0, 0);
      }
    }
    __syncthreads();
  }
#pragma unroll
  for (int t = 0; t < 5; ++t) {
    int n = wh*80 + t*16 + (lane & 15);
    if (n < 152) {
      float bb = (n < 150) ? b1[n] : 0.f;
#pragma unroll
      for (int r = 0; r < 4; ++r) {
        int m = m0 + wm*16 + ((lane >> 4) << 2) + r;
        float v = acc[t][r] + bb;
        h1a[(size_t)m*152 + n] = (n < 150) ? fmaxf(v, 0.f) : 0.f;
      }
    }
  }
}

// ---------------------------------------------------------------------------
// attn layers 2+3
// ---------------------------------------------------------------------------
__global__ __launch_bounds__(256) void k_attn2(
    const float* __restrict__ h1a, const float* __restrict__ W2p,
    const float* __restrict__ b2, const float* __restrict__ w3,
    const float* __restrict__ b3, float* __restrict__ attn) {
  __shared__ float hs[8][152];
  const int tid = threadIdx.x;
  const int t0 = blockIdx.x * 8;
  for (int t = tid; t < 304; t += 256)
    ((float4*)&hs[0][0])[t] = ((const float4*)(h1a + (size_t)t0*152))[t];
  __syncthreads();
  const int sp = tid >> 5, hb = tid & 31;
  float a2[5] = {0.f,0.f,0.f,0.f,0.f};
  for (int k = 0; k < 150; ++k) {
    float x = hs[sp][k];
#pragma unroll
    for (int q = 0; q < 5; ++q) a2[q] = fmaf(x, W2p[k*160 + hb + 32*q], a2[q]);
  }
  float p = 0.f;
#pragma unroll
  for (int q = 0; q < 5; ++q) {
    int h = hb + 32*q;
    if (h < 150) p += fmaxf(a2[q] + b2[h], 0.f) * w3[h];
  }
  p += __shfl_xor(p, 16, 32);
  p += __shfl_xor(p, 8, 32);
  p += __shfl_xor(p, 4, 32);
  p += __shfl_xor(p, 2, 32);
  p += __shfl_xor(p, 1, 32);
  if (hb == 0) attn[t0 + sp] = p + b3[0];
}

// ---------------------------------------------------------------------------
// g[s] = [e[start], e[end], span_sum]; also writes gkg (k-grouped bf16):
// gkg[(col>>3)*256*8 + s*8 + (col&7)] = bf16(g[s][col])
// ---------------------------------------------------------------------------
__global__ __launch_bounds__(256) void k_spans(
    const float* __restrict__ e, const float* __restrict__ attn,
    const int* __restrict__ sstart, const int* __restrict__ swidth,
    float* __restrict__ g, u16* __restrict__ gkg) {
  const int s = blockIdx.x;
  int st = sstart[s];
  int en = st + swidth[s];
  if (en > 2047) en = 2047;
  if (en < 0) en = 0;
  const int tid = threadIdx.x;
  for (int d = tid; d < 768; d += 256) {
    float v0 = e[(size_t)st*768 + d];
    float v1 = e[(size_t)en*768 + d];
    float acc = 0.f;
    for (int t = st; t <= en; ++t) acc += e[(size_t)t*768 + d] * attn[t];
    g[s*2304 + d]        = v0;
    g[s*2304 + 768 + d]  = v1;
    g[s*2304 + 1536 + d] = acc;
    int c0 = d, c1 = 768 + d, c2 = 1536 + d;
    gkg[((size_t)(c0>>3)*256 + s)*8 + (c0&7)] = f2bf(v0);
    gkg[((size_t)(c1>>3)*256 + s)*8 + (c1&7)] = f2bf(v1);
    gkg[((size_t)(c2>>3)*256 + s)*8 + (c2&7)] = f2bf(acc);
  }
}

// ---------------------------------------------------------------------------
// span layer1 (split-bf16 MFMA GEMM): [mh1 | hi | hj] = g @ [mW1|Wa|Wb]
// ---------------------------------------------------------------------------
__global__ __launch_bounds__(128) void k_span1(
    const float* __restrict__ g, const u16* __restrict__ Wh,
    const u16* __restrict__ Wl, const float* __restrict__ mb1,
    float* __restrict__ mh1, float* __restrict__ hi, float* __restrict__ hj) {
  __shared__ u16 lXh[16*64], lXl[16*64], lWh[160*64], lWl[160*64];
  const int tid = threadIdx.x, lane = tid & 63;
  const int wh = tid >> 6;
  const int m0 = blockIdx.x * 16;
  const int n0 = blockIdx.y * 160;
  f32x4 acc[5] = {};
  for (int e0 = 0; e0 < 2304; e0 += 64) {
    {
      int r = tid >> 3, ec = tid & 7;
      const float* src = g + (size_t)(m0 + r)*2304 + e0 + ec*8;
      float4 x0 = *(const float4*)src, x1 = *(const float4*)(src + 4);
      float xs[8] = {x0.x,x0.y,x0.z,x0.w,x1.x,x1.y,x1.z,x1.w};
      u16 hb[8], lb[8];
#pragma unroll
      for (int q = 0; q < 8; ++q) splitbf(xs[q], hb[q], lb[q]);
      int off = (r*128 + ec*16) ^ ((r & 7) << 4);
      *(uint4*)((char*)lXh + off) = make_uint4(
        (u32)hb[0]|((u32)hb[1]<<16), (u32)hb[2]|((u32)hb[3]<<16),
        (u32)hb[4]|((u32)hb[5]<<16), (u32)hb[6]|((u32)hb[7]<<16));
      *(uint4*)((char*)lXl + off) = make_uint4(
        (u32)lb[0]|((u32)lb[1]<<16), (u32)lb[2]|((u32)lb[3]<<16),
        (u32)lb[4]|((u32)lb[5]<<16), (u32)lb[6]|((u32)lb[7]<<16));
    }
#pragma unroll
    for (int t = 0; t < 10; ++t) {
      int c = tid + t*128;
      int h = c >> 3, ec = c & 7;
      int off = (h*128 + ec*16) ^ ((h & 7) << 4);
      *(uint4*)((char*)lWh + off) = *(const uint4*)(Wh + (size_t)(n0 + h)*2304 + e0 + ec*8);
      *(uint4*)((char*)lWl + off) = *(const uint4*)(Wl + (size_t)(n0 + h)*2304 + e0 + ec*8);
    }
    __syncthreads();
#pragma unroll
    for (int ks = 0; ks < 2; ++ks) {
      int eb = ks*64 + ((lane >> 4) << 4);
      int ar = lane & 15;
      bf16x8 Ah = *(const bf16x8*)((const char*)lXh + ((ar*128 + eb) ^ ((ar & 7) << 4)));
      bf16x8 Al = *(const bf16x8*)((const char*)lXl + ((ar*128 + eb) ^ ((ar & 7) << 4)));
#pragma unroll
      for (int t = 0; t < 5; ++t) {
        int br = wh*80 + t*16 + (lane & 15);
        bf16x8 Bh = *(const bf16x8*)((const char*)lWh + ((br*128 + eb) ^ ((br & 7) << 4)));
        bf16x8 Bl = *(const bf16x8*)((const char*)lWl + ((br*128 + eb) ^ ((br & 7) << 4)));
        acc[t] = __builtin_amdgcn_mfma_f32_16x16x32_bf16(Ah, Bh, acc[t], 0, 0, 0);
        acc[t] = __builtin_amdgcn_mfma_f32_16x16x32_bf16(Al, Bh, acc[t], 0, 0, 0);
        acc[t] = __builtin_amdgcn_mfma_f32_16x16x32_bf16(Ah, Bl, acc[t], 0, 0, 0);
      }
    }
    __syncthreads();
  }
#pragma unroll
  for (int t = 0; t < 5; ++t) {
    int nc = n0 + wh*80 + t*16 + (lane & 15);
#pragma unroll
    for (int r = 0; r < 4; ++r) {
      int m = m0 + ((lane >> 4) << 2) + r;
      float c = acc[t][r];
      if (nc < 160)      mh1[(size_t)m*160 + nc] = (nc < 150) ? fmaxf(c + mb1[nc], 0.f) : 0.f;
      else if (nc < 320) hi[(size_t)m*160 + (nc - 160)] = c;
      else               hj[(size_t)m*160 + (nc - 320)] = c;
    }
  }
}

// ---------------------------------------------------------------------------
// span layers 2+3
// ---------------------------------------------------------------------------
__global__ __launch_bounds__(256) void k_span2(
    const float* __restrict__ mh1, const float* __restrict__ W2p,
    const float* __restrict__ b2, const float* __restrict__ w3,
    const float* __restrict__ b3, float* __restrict__ mo) {
  __shared__ float hs[8][160];
  const int tid = threadIdx.x;
  const int s0 = blockIdx.x * 8;
  for (int t = tid; t < 320; t += 256)
    ((float4*)&hs[0][0])[t] = ((const float4*)(mh1 + (size_t)s0*160))[t];
  __syncthreads();
  const int sp = tid >> 5, hb = tid & 31;
  float a2[5] = {0.f,0.f,0.f,0.f,0.f};
  for (int k = 0; k < 150; ++k) {
    float x = hs[sp][k];
#pragma unroll
    for (int q = 0; q < 5; ++q) a2[q] = fmaf(x, W2p[k*160 + hb + 32*q], a2[q]);
  }
  float p = 0.f;
#pragma unroll
  for (int q = 0; q < 5; ++q) {
    int h = hb + 32*q;
    if (h < 150) p += fmaxf(a2[q] + b2[h], 0.f) * w3[h];
  }
  p += __shfl_xor(p, 16, 32);
  p += __shfl_xor(p, 8, 32);
  p += __shfl_xor(p, 4, 32);
  p += __shfl_xor(p, 2, 32);
  p += __shfl_xor(p, 1, 32);
  if (hb == 0) mo[s0 + sp] = p + b3[0];
}

// ---------------------------------------------------------------------------
// Fused big einsum + pairwise MLP epilogue. Block = (jt in {0,1}, i in 0..255),
// tile 128j x 160h, 4 waves (wj x wh), wave 64j x 80h (4x5 16x16x32 frags).
// GEMM1: hij-slab = g_bf16[j-tile] @ (g[i] .* Wc)   [A via global_load_lds,
//        k-grouped LDS planes, double-buffered, ONE barrier per K-chunk]
// then h1 = relu(hij + hi[i] + hj[j] + pb1) -> LDS bf16 (k-grouped)
// GEMM2: h2 = h1 @ pW2 ; s = relu(h2+pb2).w3p ; out = clip((m_i+m_j+s)/3)
// LDS map (bytes): GEMM1 A dbuf 0/16384, B dbuf 32768/53248 (total 73728)
//                  GEMM2 h1' 0..40959, B2 40960..61439, sred 61440..62463
// ---------------------------------------------------------------------------
__global__ __launch_bounds__(256) void k_hij2(
    const float* __restrict__ g, const u16* __restrict__ gkg,
    const u16* __restrict__ Wckg, const float* __restrict__ hi,
    const float* __restrict__ hj, const float* __restrict__ pb1p,
    const u16* __restrict__ W2kg, const float* __restrict__ pb2p,
    const float* __restrict__ w3p, const float* __restrict__ pb3,
    const float* __restrict__ mv, float* __restrict__ out) {
  __shared__ __align__(16) char smem[73728];
  const int tid = threadIdx.x, lane = tid & 63, w = tid >> 6;
  const int wj = w & 1, wh = w >> 1;
  const int i = blockIdx.y, j0 = blockIdx.x * 128;

  f32x4 acc[4][5] = {};

  // ---- GEMM1 over K=2304, 36 chunks of 64 ----
  auto stageA = [&](int buf, int t) {
    const int eg0 = t * 8;
    char* base = smem + buf * 16384;
#pragma unroll
    for (int q = 0; q < 4; ++q) {
      int idx = w * 4 + q, kg = idx >> 1, seg = idx & 1;
      const u16* src = gkg + ((size_t)(eg0 + kg) * 256 + (j0 + seg * 64 + lane)) * 8;
      gload_lds16(src, base + (kg * 128 + seg * 64) * 16);
    }
  };
  auto stageB = [&](int buf, int t) {
    char* base = smem + 32768 + buf * 20480;
    const float* gi = g + (size_t)i * 2304 + t * 64;
    const u16* wc = Wckg + (size_t)t * 8 * 1280;
#pragma unroll
    for (int k = 0; k < 5; ++k) {
      int tg = k * 256 + tid;
      int grp = tg / 160, h = tg - grp * 160;
      uint4 wv = *(const uint4*)(wc + ((size_t)grp * 160 + h) * 8);
      float4 s0 = *(const float4*)(gi + grp * 8);
      float4 s1 = *(const float4*)(gi + grp * 8 + 4);
      uint4 r;
      r.x = cvtpk(bflo(wv.x) * s0.x, bfhi(wv.x) * s0.y);
      r.y = cvtpk(bflo(wv.y) * s0.z, bfhi(wv.y) * s0.w);
      r.z = cvtpk(bflo(wv.z) * s1.x, bfhi(wv.z) * s1.y);
      r.w = cvtpk(bflo(wv.w) * s1.z, bfhi(wv.w) * s1.w);
      *(uint4*)(base + grp * 2560 + h * 16) = r;
    }
  };

  stageA(0, 0);
  stageB(0, 0);
  __syncthreads();
  for (int t = 0; t < 36; ++t) {
    int cur = t & 1;
    if (t < 35) { stageA(cur ^ 1, t + 1); stageB(cur ^ 1, t + 1); }
    const char* Ab = smem + cur * 16384;
    const char* Bb = smem + 32768 + cur * 20480;
#pragma unroll
    for (int ks = 0; ks < 2; ++ks) {
      int kgl = ks * 4 + (lane >> 4);
      bf16x8 af[4], bfr[5];
#pragma unroll
      for (int q = 0; q < 4; ++q)
        af[q] = *(const bf16x8*)(Ab + (kgl * 128 + wj * 64 + q * 16 + (lane & 15)) * 16);
#pragma unroll
      for (int u = 0; u < 5; ++u)
        bfr[u] = *(const bf16x8*)(Bb + kgl * 2560 + (wh * 80 + u * 16 + (lane & 15)) * 16);
#pragma unroll
      for (int q = 0; q < 4; ++q)
#pragma unroll
        for (int u = 0; u < 5; ++u)
          acc[q][u] = __builtin_amdgcn_mfma_f32_16x16x32_bf16(af[q], bfr[u], acc[q][u], 0, 0, 0);
    }
    __syncthreads();
  }

  // ---- epilogue1: h1 = relu(hij + hi + hj + pb1) -> LDS bf16 [20][128][8] ----
  {
    float hib[5];
#pragma unroll
    for (int u = 0; u < 5; ++u) {
      int h = wh * 80 + u * 16 + (lane & 15);
      hib[u] = hi[i * 160 + h] + pb1p[h];
    }
#pragma unroll
    for (int q = 0; q < 4; ++q) {
      int jl = wj * 64 + q * 16 + ((lane >> 4) << 2);
#pragma unroll
      for (int r = 0; r < 4; ++r) {
        const float* hjr = hj + (size_t)(j0 + jl + r) * 160;
#pragma unroll
        for (int u = 0; u < 5; ++u) {
          int h = wh * 80 + u * 16 + (lane & 15);
          float v = fmaxf(acc[q][u][r] + hib[u] + hjr[h], 0.f);
          *(u16*)(smem + (h >> 3) * 2048 + (jl + r) * 16 + (h & 7) * 2) = f2bf(v);
        }
      }
    }
  }
  __syncthreads();

  // ---- GEMM2: h2 = h1' @ W2 (K=160), 3 chunks (8,8,4 kgrps) ----
  f32x4 acc2[4][5] = {};
  for (int c = 0; c < 3; ++c) {
    const int kgs = (c < 2) ? 8 : 4;
    const int nloads = kgs * 5 / 2;   // kgs*2560/1024
    for (int q = w; q < nloads; q += 4) {
      const u16* src = W2kg + (size_t)c * 10240 + q * 512 + lane * 8;
      gload_lds16(src, smem + 40960 + q * 1024);
    }
    __syncthreads();
    const int nks = (c < 2) ? 2 : 1;
    for (int ks = 0; ks < nks; ++ks) {
      int kgl = ks * 4 + (lane >> 4);
      bf16x8 af[4], bfr[5];
#pragma unroll
      for (int q = 0; q < 4; ++q)
        af[q] = *(const bf16x8*)(smem + ((c * 8 + kgl) * 128 + wj * 64 + q * 16 + (lane & 15)) * 16);
#pragma unroll
      for (int u = 0; u < 5; ++u)
        bfr[u] = *(const bf16x8*)(smem + 40960 + kgl * 2560 + (wh * 80 + u * 16 + (lane & 15)) * 16);
#pragma unroll
      for (int q = 0; q < 4; ++q)
#pragma unroll
        for (int u = 0; u < 5; ++u)
          acc2[q][u] = __builtin_amdgcn_mfma_f32_16x16x32_bf16(af[q], bfr[u], acc2[q][u], 0, 0, 0);
    }
    __syncthreads();
  }

  // ---- epilogue2: s[j] = relu(h2 + pb2) . w3 ; out = clip((mi+mj+s)/3) ----
  {
    float w3v[5], b2v[5];
#pragma unroll
    for (int u = 0; u < 5; ++u) {
      int h2 = wh * 80 + u * 16 + (lane & 15);
      w3v[u] = w3p[h2];
      b2v[u] = pb2p[h2];
    }
#pragma unroll
    for (int q = 0; q < 4; ++q) {
#pragma unroll
      for (int r = 0; r < 4; ++r) {
        float sp = 0.f;
#pragma unroll
        for (int u = 0; u < 5; ++u)
          sp += fmaxf(acc2[q][u][r] + b2v[u], 0.f) * w3v[u];
        sp += __shfl_xor(sp, 1);
        sp += __shfl_xor(sp, 2);
        sp += __shfl_xor(sp, 4);
        sp += __shfl_xor(sp, 8);
        if ((lane & 15) == 0) {
          int jl = wj * 64 + q * 16 + ((lane >> 4) << 2) + r;
          *(float*)(smem + 61440 + (jl * 2 + wh) * 4) = sp;
        }
      }
    }
  }
  __syncthreads();
  if (tid < 128) {
    float s = *(const float*)(smem + 61440 + tid * 8) +
              *(const float*)(smem + 61440 + tid * 8 + 4) + pb3[0];
    int j = j0 + tid;
    float v = (mv[i] + mv[j] + s) * (1.f / 3.f);
    v = fminf(fmaxf(v, 0.f), 1.f);
    out[i * 256 + j] = v;
  }
}

// ---------------------------------------------------------------------------
extern "C" void kernel_launch(void* const* d_in, const int* in_sizes, int n_in,
                              void* d_out, int out_size, void* d_ws, size_t ws_size,
                              hipStream_t stream) {
  (void)in_sizes; (void)n_in; (void)out_size; (void)ws_size;
  const float* e    = (const float*)d_in[0];
  const int*   sst  = (const int*)d_in[1];
  const int*   swd  = (const int*)d_in[2];
  const float* aW1  = (const float*)d_in[3];
  const float* ab1  = (const float*)d_in[4];
  const float* aW2  = (const float*)d_in[5];
  const float* ab2  = (const float*)d_in[6];
  const float* aW3  = (const float*)d_in[7];
  const float* ab3  = (const float*)d_in[8];
  const float* mW1  = (const float*)d_in[9];
  const float* mb1  = (const float*)d_in[10];
  const float* mW2  = (const float*)d_in[11];
  const float* mb2  = (const float*)d_in[12];
  const float* mW3  = (const float*)d_in[13];
  const float* mb3  = (const float*)d_in[14];
  const float* pW1  = (const float*)d_in[15];
  const float* pb1  = (const float*)d_in[16];
  const float* pW2  = (const float*)d_in[17];
  const float* pb2  = (const float*)d_in[18];
  const float* pW3  = (const float*)d_in[19];
  const float* pb3  = (const float*)d_in[20];
  float* out = (float*)d_out;

  char* ws = (char*)d_ws;
  size_t off = 0;
  auto alloc = [&](size_t bytes) -> char* {
    char* p = ws + off;
    off += (bytes + 255) & ~(size_t)255;
    return p;
  };
  float* attn  = (float*)alloc(2048ULL*4);
  float* g     = (float*)alloc(256ULL*2304*4);
  float* hi    = (float*)alloc(256ULL*160*4);
  float* hj    = (float*)alloc(256ULL*160*4);
  float* mv    = (float*)alloc(256ULL*4);
  float* h1a   = (float*)alloc(2048ULL*152*4);
  float* mh1   = (float*)alloc(256ULL*160*4);
  u16*   aW1Th = (u16*)alloc(160ULL*768*2);
  u16*   aW1Tl = (u16*)alloc(160ULL*768*2);
  u16*   Wcath = (u16*)alloc(480ULL*2304*2);
  u16*   Wcatl = (u16*)alloc(480ULL*2304*2);
  float* aW2p  = (float*)alloc(152ULL*160*4);
  float* mW2p  = (float*)alloc(152ULL*160*4);
  u16*   gkg   = (u16*)alloc(288ULL*256*8*2);
  u16*   Wckg  = (u16*)alloc(288ULL*160*8*2);
  u16*   W2kg  = (u16*)alloc(20ULL*160*8*2);
  float* pb1p  = (float*)alloc(160ULL*4);
  float* pb2p  = (float*)alloc(160ULL*4);
  float* w3p   = (float*)alloc(160ULL*4);

  k_prep<<<1024, 256, 0, stream>>>(aW1, mW1, pW1, aW2, mW2, pW2, pb1, pb2, pW3,
                                   aW1Th, aW1Tl, Wcath, Wcatl, aW2p, mW2p,
                                   Wckg, W2kg, pb1p, pb2p, w3p);
  k_attn1<<<64, 256, 0, stream>>>(e, aW1Th, aW1Tl, ab1, h1a);
  k_attn2<<<256, 256, 0, stream>>>(h1a, aW2p, ab2, aW3, ab3, attn);
  k_spans<<<256, 256, 0, stream>>>(e, attn, sst, swd, g, gkg);
  k_span1<<<dim3(16, 3), 128, 0, stream>>>(g, Wcath, Wcatl, mb1, mh1, hi, hj);
  k_span2<<<32, 256, 0, stream>>>(mh1, mW2p, mb2, mW3, mb3, mv);
  k_hij2<<<dim3(2, 256), 256, 0, stream>>>(g, gkg, Wckg, hi, hj, pb1p,
                                           W2kg, pb2p, w3p, pb3, mv, out);
}